// Round 1
// baseline (467.637 us; speedup 1.0000x reference)
//
#include <hip/hip_runtime.h>
#include <hip/hip_bf16.h>

#define N_NODES 100000
#define N_EDGES 1600000
#define D_IN    256
#define D_OUT_T 512      // 8 heads * 64, concatenated
#define MPAD    100096   // 782 * 128

#define BM 128
#define BN 128
#define BK 64

typedef __attribute__((ext_vector_type(4))) float f32x4;
typedef __attribute__((ext_vector_type(8))) short bf16x8;
typedef __attribute__((ext_vector_type(4))) unsigned short u16x4;

__device__ __forceinline__ float bf2f(unsigned short u) {
    union { unsigned int i; float f; } x; x.i = ((unsigned int)u) << 16; return x.f;
}
__device__ __forceinline__ unsigned short f2bf(float f) {
    union { float f; unsigned int i; } x; x.f = f;
    unsigned int i = x.i;
    return (unsigned short)((i + 0x7FFFu + ((i >> 16) & 1u)) >> 16);  // RNE
}

// ---------------- h (fp32) -> bf16 ----------------
__global__ void k_h2b(const float* __restrict__ h, unsigned short* __restrict__ hb) {
    int i = blockIdx.x * 256 + threadIdx.x;           // over 6.4M float4 groups
    if (i >= N_NODES * (D_IN / 4)) return;
    f32x4 v = ((const f32x4*)h)[i];
    u16x4 o; o.x = f2bf(v.x); o.y = f2bf(v.y); o.z = f2bf(v.z); o.w = f2bf(v.w);
    ((u16x4*)hb)[i] = o;
}

// ---------------- W [8][256][64] fp32 -> WcT [512][256] bf16 ----------------
// WcT[h*64+j][d] = W[h][d][j]
__global__ void k_wct(const float* __restrict__ W, unsigned short* __restrict__ WcT) {
    int t = blockIdx.x * 256 + threadIdx.x;
    if (t >= 8 * 256 * 64) return;
    int hh = t >> 14;
    int rem = t & 16383;
    int d = rem >> 6;
    int j = rem & 63;
    WcT[(size_t)(hh * 64 + j) * 256 + d] = f2bf(W[t]);
}

// ---------------- degree count (deg aliased onto rowptr[0..N)) ----------------
__global__ void k_deg(const int* __restrict__ erow, int* __restrict__ deg) {
    int i = blockIdx.x * 256 + threadIdx.x;
    if (i < N_EDGES) atomicAdd(&deg[erow[i]], 1);
}

// ---------------- 3-kernel exclusive scan over deg -> rowptr ----------------
__global__ void k_scan1(int* __restrict__ deg, int* __restrict__ bsum) {
    __shared__ int sm[256];
    int t = threadIdx.x, i = blockIdx.x * 256 + t;
    int v = (i < N_NODES) ? deg[i] : 0;
    sm[t] = v; __syncthreads();
    #pragma unroll
    for (int o = 1; o < 256; o <<= 1) {
        int x = (t >= o) ? sm[t - o] : 0;
        __syncthreads();
        sm[t] += x;
        __syncthreads();
    }
    if (i < N_NODES) deg[i] = sm[t] - v;      // exclusive within block
    if (t == 255) bsum[blockIdx.x] = sm[255]; // block total
}
__global__ void k_scan2(int* __restrict__ bsum, int nb) {
    __shared__ int sm[512];
    int t = threadIdx.x;
    int v = (t < nb) ? bsum[t] : 0;
    sm[t] = v; __syncthreads();
    #pragma unroll
    for (int o = 1; o < 512; o <<= 1) {
        int x = (t >= o) ? sm[t - o] : 0;
        __syncthreads();
        sm[t] += x;
        __syncthreads();
    }
    if (t < nb) bsum[t] = sm[t] - v;          // exclusive block offsets
}
__global__ void k_scan3(int* __restrict__ rowptr, const int* __restrict__ bsum,
                        int* __restrict__ cursor) {
    int i = blockIdx.x * 256 + threadIdx.x;
    if (i < N_NODES) {
        int v = rowptr[i] + bsum[blockIdx.x];
        rowptr[i] = v;
        cursor[i] = v;
    }
    if (i == 0) rowptr[N_NODES] = N_EDGES;
}

// ---------------- CSR fill ----------------
__global__ void k_fill(const int* __restrict__ erow, const int* __restrict__ ecol,
                       int* __restrict__ cursor, int* __restrict__ colidx) {
    int i = blockIdx.x * 256 + threadIdx.x;
    if (i < N_EDGES) {
        int p = atomicAdd(&cursor[erow[i]], 1);
        colidx[p] = ecol[i];
    }
}

// ---------------- aggregation: one wave per node ----------------
// hagg[n] = (1/deg) * sum_{e in row n} src[col[e]]   (bf16 out, fp32 accum)
template <bool BF16SRC>
__global__ __launch_bounds__(256) void k_agg(const void* __restrict__ src,
                                             const int* __restrict__ rowptr,
                                             const int* __restrict__ colidx,
                                             unsigned short* __restrict__ hagg) {
    int wid = blockIdx.x * 4 + (threadIdx.x >> 6);
    int lane = threadIdx.x & 63;
    if (wid >= N_NODES) return;
    int s = rowptr[wid], e = rowptr[wid + 1];
    float a0 = 0.f, a1 = 0.f, a2 = 0.f, a3 = 0.f;
    for (int p = s; p < e; ++p) {
        int c = colidx[p];
        if constexpr (BF16SRC) {
            u16x4 v = *((const u16x4*)((const unsigned short*)src + ((size_t)c << 8)) + lane);
            a0 += bf2f(v.x); a1 += bf2f(v.y); a2 += bf2f(v.z); a3 += bf2f(v.w);
        } else {
            f32x4 v = *((const f32x4*)((const float*)src + ((size_t)c << 8)) + lane);
            a0 += v.x; a1 += v.y; a2 += v.z; a3 += v.w;
        }
    }
    float inv = (e > s) ? 1.0f / (float)(e - s) : 0.0f;
    u16x4 o;
    o.x = f2bf(a0 * inv); o.y = f2bf(a1 * inv); o.z = f2bf(a2 * inv); o.w = f2bf(a3 * inv);
    *((u16x4*)(hagg + ((size_t)wid << 8)) + lane) = o;
}

// ---------------- GEMM: C[M x 512] = hagg[M x 256] * Wc[256 x 512] ----------------
// A = hagg row-major [MPAD][256] bf16; B = WcT row-major [512][256] bf16 (i.e. Wc^T)
// 128x128 block tile, 4 waves (2x2), each wave 64x64, BK=64, 16x16x32 bf16 MFMA.
// LDS tiles stored as [rows][64] with 16B-chunk XOR swizzle (chunk ^= row&7):
// linear global_load_lds dest + inverse-swizzled global src + swizzled ds_read.
__global__ __launch_bounds__(256, 2) void k_gemm(const unsigned short* __restrict__ A,
                                                 const unsigned short* __restrict__ B,
                                                 float* __restrict__ C, int M) {
    __shared__ __align__(16) unsigned short As[BM * BK];
    __shared__ __align__(16) unsigned short Bs[BN * BK];
    const int tid  = threadIdx.x;
    const int wave = tid >> 6;
    const int lane = tid & 63;
    const int M0 = blockIdx.x * BM;
    const int N0 = blockIdx.y * BN;
    const int wm = (wave >> 1) * 64;
    const int wn = (wave & 1) * 64;

    f32x4 acc[4][4] = {};

    for (int kk = 0; kk < D_IN; kk += BK) {
        __syncthreads();  // previous-iteration LDS reads done before overwrite
        #pragma unroll
        for (int i = 0; i < 4; ++i) {  // stage A tile: 128 rows x 64 k
            int rbase = i * 32 + wave * 8;
            int r = rbase + (lane >> 3);
            int gc = (lane & 7) ^ (r & 7);  // inverse-swizzled source chunk
            const unsigned short* g = A + (size_t)(M0 + r) * D_IN + kk + gc * 8;
            __builtin_amdgcn_global_load_lds(
                (const __attribute__((address_space(1))) void*)g,
                (__attribute__((address_space(3))) void*)(As + rbase * 64), 16, 0, 0);
        }
        #pragma unroll
        for (int i = 0; i < 4; ++i) {  // stage B tile: 128 cols x 64 k
            int rbase = i * 32 + wave * 8;
            int r = rbase + (lane >> 3);
            int gc = (lane & 7) ^ (r & 7);
            const unsigned short* g = B + (size_t)(N0 + r) * D_IN + kk + gc * 8;
            __builtin_amdgcn_global_load_lds(
                (const __attribute__((address_space(1))) void*)g,
                (__attribute__((address_space(3))) void*)(Bs + rbase * 64), 16, 0, 0);
        }
        __syncthreads();

        #pragma unroll
        for (int ks = 0; ks < 2; ++ks) {
            bf16x8 a[4], b[4];
            #pragma unroll
            for (int m = 0; m < 4; ++m) {
                int r = wm + m * 16 + (lane & 15);
                int lc = (ks * 4 + (lane >> 4)) ^ (r & 7);  // swizzled read chunk
                a[m] = *(const bf16x8*)(As + r * 64 + lc * 8);
            }
            #pragma unroll
            for (int n = 0; n < 4; ++n) {
                int c = wn + n * 16 + (lane & 15);
                int lc = (ks * 4 + (lane >> 4)) ^ (c & 7);
                b[n] = *(const bf16x8*)(Bs + c * 64 + lc * 8);
            }
            #pragma unroll
            for (int m = 0; m < 4; ++m)
                #pragma unroll
                for (int n = 0; n < 4; ++n)
                    acc[m][n] = __builtin_amdgcn_mfma_f32_16x16x32_bf16(
                        a[m], b[n], acc[m][n], 0, 0, 0);
        }
    }

    // C/D layout: col = lane&15, row = (lane>>4)*4 + reg
    #pragma unroll
    for (int m = 0; m < 4; ++m) {
        #pragma unroll
        for (int i = 0; i < 4; ++i) {
            int row = M0 + wm + m * 16 + (lane >> 4) * 4 + i;
            if (row < M) {
                #pragma unroll
                for (int n = 0; n < 4; ++n) {
                    int col = N0 + wn + n * 16 + (lane & 15);
                    C[(size_t)row * D_OUT_T + col] = acc[m][n][i];
                }
            }
        }
    }
}

extern "C" void kernel_launch(void* const* d_in, const int* in_sizes, int n_in,
                              void* d_out, int out_size, void* d_ws, size_t ws_size,
                              hipStream_t stream) {
    const float* h  = (const float*)d_in[0];
    const float* W  = (const float*)d_in[1];
    const int* erow = (const int*)d_in[2];
    const int* ecol = erow + N_EDGES;
    float* out = (float*)d_out;

    char* base = (char*)d_ws;
    size_t off = 0;
    auto alloc = [&](size_t b) {
        char* p = base + off;
        off += (b + 255) & ~(size_t)255;
        return p;
    };
    int* rowptr = (int*)alloc((N_NODES + 1) * sizeof(int));  // doubles as deg
    int* cursor = (int*)alloc(N_NODES * sizeof(int));
    int* bsum   = (int*)alloc(512 * sizeof(int));
    int* colidx = (int*)alloc((size_t)N_EDGES * sizeof(int));
    unsigned short* WcT  = (unsigned short*)alloc((size_t)D_OUT_T * D_IN * 2);
    unsigned short* hagg = (unsigned short*)alloc((size_t)MPAD * D_IN * 2);
    unsigned short* hb   = (unsigned short*)alloc((size_t)N_NODES * D_IN * 2);
    bool use_hb = (off <= ws_size);  // fall back to fp32 gather if ws too small

    hipMemsetAsync(rowptr, 0, (N_NODES + 1) * sizeof(int), stream);

    if (use_hb)
        k_h2b<<<(N_NODES * (D_IN / 4) + 255) / 256, 256, 0, stream>>>(h, hb);
    k_wct<<<(8 * 256 * 64 + 255) / 256, 256, 0, stream>>>(W, WcT);
    k_deg<<<(N_EDGES + 255) / 256, 256, 0, stream>>>(erow, rowptr);

    const int NB = (N_NODES + 255) / 256;  // 391
    k_scan1<<<NB, 256, 0, stream>>>(rowptr, bsum);
    k_scan2<<<1, 512, 0, stream>>>(bsum, NB);
    k_scan3<<<NB, 256, 0, stream>>>(rowptr, bsum, cursor);
    k_fill<<<(N_EDGES + 255) / 256, 256, 0, stream>>>(erow, ecol, cursor, colidx);

    if (use_hb)
        k_agg<true><<<(N_NODES + 3) / 4, 256, 0, stream>>>(hb, rowptr, colidx, hagg);
    else
        k_agg<false><<<(N_NODES + 3) / 4, 256, 0, stream>>>(h, rowptr, colidx, hagg);

    dim3 grid(MPAD / BM, 4);
    k_gemm<<<grid, 256, 0, stream>>>(hagg, WcT, out, N_NODES);
}

// Round 2
// 388.688 us; speedup vs baseline: 1.2031x; 1.2031x over previous
//
#include <hip/hip_runtime.h>
#include <hip/hip_bf16.h>

#define N_NODES 100000
#define N_EDGES 1600000
#define D_IN    256
#define D_OUT_T 512      // 8 heads * 64, concatenated
#define MPAD    100096   // 782 * 128

#define BM 128
#define BN 128
#define BK 64

#define NB_H2B 25000     // N_NODES*(D_IN/4)/256
#define NB_WCT 512       // 8*256*64/256
#define NB_DEG 6250      // N_EDGES/256

typedef __attribute__((ext_vector_type(4))) float f32x4;
typedef __attribute__((ext_vector_type(8))) short bf16x8;
typedef __attribute__((ext_vector_type(4))) unsigned short u16x4;

__device__ __forceinline__ float bf2f(unsigned short u) {
    union { unsigned int i; float f; } x; x.i = ((unsigned int)u) << 16; return x.f;
}
__device__ __forceinline__ unsigned short f2bf(float f) {
    union { float f; unsigned int i; } x; x.f = f;
    unsigned int i = x.i;
    return (unsigned short)((i + 0x7FFFu + ((i >> 16) & 1u)) >> 16);  // RNE
}
__device__ __forceinline__ f32x4 cv4(u16x4 v) {
    f32x4 r; r.x = bf2f(v.x); r.y = bf2f(v.y); r.z = bf2f(v.z); r.w = bf2f(v.w);
    return r;
}

// ---------------- fused preprocessing: h->bf16 | W->WcT bf16 | degree count ----
// WcT[h*64+j][d] = W[h][d][j];  deg via atomics (deg aliased onto rowptr[0..N))
__global__ void k_pre(const float* __restrict__ h, unsigned short* __restrict__ hb,
                      const float* __restrict__ W, unsigned short* __restrict__ WcT,
                      const int* __restrict__ erow, int* __restrict__ deg,
                      int do_hb) {
    int b = blockIdx.x;
    if (b < NB_H2B) {
        if (!do_hb) return;
        int i = b * 256 + threadIdx.x;                 // 6.4M float4 groups
        f32x4 v = ((const f32x4*)h)[i];
        u16x4 o; o.x = f2bf(v.x); o.y = f2bf(v.y); o.z = f2bf(v.z); o.w = f2bf(v.w);
        ((u16x4*)hb)[i] = o;
    } else if (b < NB_H2B + NB_WCT) {
        int t = (b - NB_H2B) * 256 + threadIdx.x;      // 131072
        int hh = t >> 14;
        int rem = t & 16383;
        int d = rem >> 6;
        int j = rem & 63;
        WcT[(size_t)(hh * 64 + j) * 256 + d] = f2bf(W[t]);
    } else {
        int i = (b - NB_H2B - NB_WCT) * 256 + threadIdx.x;
        if (i < N_EDGES) atomicAdd(&deg[erow[i]], 1);
    }
}

// ---------------- 3-kernel exclusive scan over deg -> rowptr ----------------
__global__ void k_scan1(int* __restrict__ deg, int* __restrict__ bsum) {
    __shared__ int sm[256];
    int t = threadIdx.x, i = blockIdx.x * 256 + t;
    int v = (i < N_NODES) ? deg[i] : 0;
    sm[t] = v; __syncthreads();
    #pragma unroll
    for (int o = 1; o < 256; o <<= 1) {
        int x = (t >= o) ? sm[t - o] : 0;
        __syncthreads();
        sm[t] += x;
        __syncthreads();
    }
    if (i < N_NODES) deg[i] = sm[t] - v;      // exclusive within block
    if (t == 255) bsum[blockIdx.x] = sm[255]; // block total
}
__global__ void k_scan2(int* __restrict__ bsum, int nb) {
    __shared__ int sm[512];
    int t = threadIdx.x;
    int v = (t < nb) ? bsum[t] : 0;
    sm[t] = v; __syncthreads();
    #pragma unroll
    for (int o = 1; o < 512; o <<= 1) {
        int x = (t >= o) ? sm[t - o] : 0;
        __syncthreads();
        sm[t] += x;
        __syncthreads();
    }
    if (t < nb) bsum[t] = sm[t] - v;          // exclusive block offsets
}
__global__ void k_scan3(int* __restrict__ rowptr, const int* __restrict__ bsum,
                        int* __restrict__ cursor) {
    int i = blockIdx.x * 256 + threadIdx.x;
    if (i < N_NODES) {
        int v = rowptr[i] + bsum[blockIdx.x];
        rowptr[i] = v;
        cursor[i] = v;
    }
    if (i == 0) rowptr[N_NODES] = N_EDGES;
}

// ---------------- CSR fill ----------------
__global__ void k_fill(const int* __restrict__ erow, const int* __restrict__ ecol,
                       int* __restrict__ cursor, int* __restrict__ colidx) {
    int i = blockIdx.x * 256 + threadIdx.x;
    if (i < N_EDGES) {
        int p = atomicAdd(&cursor[erow[i]], 1);
        colidx[p] = ecol[i];
    }
}

// ---------------- aggregation: one wave per node, 4-deep MLP ----------------
// hagg[n] = (1/deg) * sum_{e in row n} src[col[e]]   (bf16 out, fp32 accum)
template <bool BF16SRC>
__global__ __launch_bounds__(256) void k_agg(const void* __restrict__ src,
                                             const int* __restrict__ rowptr,
                                             const int* __restrict__ colidx,
                                             unsigned short* __restrict__ hagg) {
    int wid = blockIdx.x * 4 + (threadIdx.x >> 6);
    int lane = threadIdx.x & 63;
    if (wid >= N_NODES) return;
    int s = rowptr[wid], e = rowptr[wid + 1];
    f32x4 acc0 = {0,0,0,0}, acc1 = {0,0,0,0}, acc2 = {0,0,0,0}, acc3 = {0,0,0,0};
    const unsigned short* hb = (const unsigned short*)src;
    const float* hf = (const float*)src;
    int p = s;
    int n4 = s + ((e - s) & ~3);
    for (; p < n4; p += 4) {
        int c0 = colidx[p + 0], c1 = colidx[p + 1];
        int c2 = colidx[p + 2], c3 = colidx[p + 3];
        if constexpr (BF16SRC) {
            u16x4 v0 = *((const u16x4*)(hb + ((size_t)c0 << 8)) + lane);
            u16x4 v1 = *((const u16x4*)(hb + ((size_t)c1 << 8)) + lane);
            u16x4 v2 = *((const u16x4*)(hb + ((size_t)c2 << 8)) + lane);
            u16x4 v3 = *((const u16x4*)(hb + ((size_t)c3 << 8)) + lane);
            acc0 += cv4(v0); acc1 += cv4(v1); acc2 += cv4(v2); acc3 += cv4(v3);
        } else {
            f32x4 v0 = *((const f32x4*)(hf + ((size_t)c0 << 8)) + lane);
            f32x4 v1 = *((const f32x4*)(hf + ((size_t)c1 << 8)) + lane);
            f32x4 v2 = *((const f32x4*)(hf + ((size_t)c2 << 8)) + lane);
            f32x4 v3 = *((const f32x4*)(hf + ((size_t)c3 << 8)) + lane);
            acc0 += v0; acc1 += v1; acc2 += v2; acc3 += v3;
        }
    }
    for (; p < e; ++p) {
        int c = colidx[p];
        if constexpr (BF16SRC) {
            u16x4 v = *((const u16x4*)(hb + ((size_t)c << 8)) + lane);
            acc0 += cv4(v);
        } else {
            f32x4 v = *((const f32x4*)(hf + ((size_t)c << 8)) + lane);
            acc0 += v;
        }
    }
    acc0 = acc0 + acc1;
    acc2 = acc2 + acc3;
    acc0 = acc0 + acc2;
    float inv = (e > s) ? 1.0f / (float)(e - s) : 0.0f;
    u16x4 o;
    o.x = f2bf(acc0.x * inv); o.y = f2bf(acc0.y * inv);
    o.z = f2bf(acc0.z * inv); o.w = f2bf(acc0.w * inv);
    *((u16x4*)(hagg + ((size_t)wid << 8)) + lane) = o;
}

// ---------------- GEMM: C[M x 512] = hagg[M x 256] * Wc[256 x 512] ----------------
// A = hagg row-major [MPAD][256] bf16; B = WcT row-major [512][256] bf16 (i.e. Wc^T)
// 128x128 block tile, 4 waves (2x2), each wave 64x64, BK=64, 16x16x32 bf16 MFMA.
// LDS tiles stored as [rows][64] with 16B-chunk XOR swizzle (chunk ^= row&7):
// linear global_load_lds dest + inverse-swizzled global src + swizzled ds_read.
// 1D grid with XCD-chunk swizzle: the 4 N-blocks sharing an A panel are
// consecutive on the same XCD -> A fetched ~once from HBM.
__global__ __launch_bounds__(256, 2) void k_gemm(const unsigned short* __restrict__ A,
                                                 const unsigned short* __restrict__ B,
                                                 float* __restrict__ C, int M) {
    __shared__ __align__(16) unsigned short As[BM * BK];
    __shared__ __align__(16) unsigned short Bs[BN * BK];
    const int orig = blockIdx.x;                   // 3128 = 782*4, 3128%8==0
    const int wgid = (orig & 7) * (3128 / 8) + (orig >> 3);
    const int M0 = (wgid >> 2) * BM;
    const int N0 = (wgid & 3) * BN;
    const int tid  = threadIdx.x;
    const int wave = tid >> 6;
    const int lane = tid & 63;
    const int wm = (wave >> 1) * 64;
    const int wn = (wave & 1) * 64;

    f32x4 acc[4][4] = {};

    for (int kk = 0; kk < D_IN; kk += BK) {
        __syncthreads();  // previous-iteration LDS reads done before overwrite
        #pragma unroll
        for (int i = 0; i < 4; ++i) {  // stage A tile: 128 rows x 64 k
            int rbase = i * 32 + wave * 8;
            int r = rbase + (lane >> 3);
            int gc = (lane & 7) ^ (r & 7);  // inverse-swizzled source chunk
            const unsigned short* g = A + (size_t)(M0 + r) * D_IN + kk + gc * 8;
            __builtin_amdgcn_global_load_lds(
                (const __attribute__((address_space(1))) void*)g,
                (__attribute__((address_space(3))) void*)(As + rbase * 64), 16, 0, 0);
        }
        #pragma unroll
        for (int i = 0; i < 4; ++i) {  // stage B tile: 128 cols x 64 k
            int rbase = i * 32 + wave * 8;
            int r = rbase + (lane >> 3);
            int gc = (lane & 7) ^ (r & 7);
            const unsigned short* g = B + (size_t)(N0 + r) * D_IN + kk + gc * 8;
            __builtin_amdgcn_global_load_lds(
                (const __attribute__((address_space(1))) void*)g,
                (__attribute__((address_space(3))) void*)(Bs + rbase * 64), 16, 0, 0);
        }
        __syncthreads();

        #pragma unroll
        for (int ks = 0; ks < 2; ++ks) {
            bf16x8 a[4], b[4];
            #pragma unroll
            for (int m = 0; m < 4; ++m) {
                int r = wm + m * 16 + (lane & 15);
                int lc = (ks * 4 + (lane >> 4)) ^ (r & 7);  // swizzled read chunk
                a[m] = *(const bf16x8*)(As + r * 64 + lc * 8);
            }
            #pragma unroll
            for (int n = 0; n < 4; ++n) {
                int c = wn + n * 16 + (lane & 15);
                int lc = (ks * 4 + (lane >> 4)) ^ (c & 7);
                b[n] = *(const bf16x8*)(Bs + c * 64 + lc * 8);
            }
            #pragma unroll
            for (int m = 0; m < 4; ++m)
                #pragma unroll
                for (int n = 0; n < 4; ++n)
                    acc[m][n] = __builtin_amdgcn_mfma_f32_16x16x32_bf16(
                        a[m], b[n], acc[m][n], 0, 0, 0);
        }
    }

    // C/D layout: col = lane&15, row = (lane>>4)*4 + reg
    #pragma unroll
    for (int m = 0; m < 4; ++m) {
        #pragma unroll
        for (int i = 0; i < 4; ++i) {
            int row = M0 + wm + m * 16 + (lane >> 4) * 4 + i;
            if (row < M) {
                #pragma unroll
                for (int n = 0; n < 4; ++n) {
                    int col = N0 + wn + n * 16 + (lane & 15);
                    C[(size_t)row * D_OUT_T + col] = acc[m][n][i];
                }
            }
        }
    }
}

extern "C" void kernel_launch(void* const* d_in, const int* in_sizes, int n_in,
                              void* d_out, int out_size, void* d_ws, size_t ws_size,
                              hipStream_t stream) {
    const float* h  = (const float*)d_in[0];
    const float* W  = (const float*)d_in[1];
    const int* erow = (const int*)d_in[2];
    const int* ecol = erow + N_EDGES;
    float* out = (float*)d_out;

    char* base = (char*)d_ws;
    size_t off = 0;
    auto alloc = [&](size_t b) {
        char* p = base + off;
        off += (b + 255) & ~(size_t)255;
        return p;
    };
    int* rowptr = (int*)alloc((N_NODES + 1) * sizeof(int));  // doubles as deg
    int* cursor = (int*)alloc(N_NODES * sizeof(int));
    int* bsum   = (int*)alloc(512 * sizeof(int));
    int* colidx = (int*)alloc((size_t)N_EDGES * sizeof(int));
    unsigned short* WcT  = (unsigned short*)alloc((size_t)D_OUT_T * D_IN * 2);
    unsigned short* hagg = (unsigned short*)alloc((size_t)MPAD * D_IN * 2);
    unsigned short* hb   = (unsigned short*)alloc((size_t)N_NODES * D_IN * 2);
    bool use_hb = (off <= ws_size);  // fall back to fp32 gather if ws too small

    hipMemsetAsync(rowptr, 0, (N_NODES + 1) * sizeof(int), stream);

    k_pre<<<NB_H2B + NB_WCT + NB_DEG, 256, 0, stream>>>(
        h, hb, W, WcT, erow, rowptr, use_hb ? 1 : 0);

    const int NB = (N_NODES + 255) / 256;  // 391
    k_scan1<<<NB, 256, 0, stream>>>(rowptr, bsum);
    k_scan2<<<1, 512, 0, stream>>>(bsum, NB);
    k_scan3<<<NB, 256, 0, stream>>>(rowptr, bsum, cursor);
    k_fill<<<(N_EDGES + 255) / 256, 256, 0, stream>>>(erow, ecol, cursor, colidx);

    if (use_hb)
        k_agg<true><<<(N_NODES + 3) / 4, 256, 0, stream>>>(hb, rowptr, colidx, hagg);
    else
        k_agg<false><<<(N_NODES + 3) / 4, 256, 0, stream>>>(h, rowptr, colidx, hagg);

    k_gemm<<<MPAD / BM * 4, 256, 0, stream>>>(hagg, WcT, out, N_NODES);
}

// Round 3
// 343.184 us; speedup vs baseline: 1.3626x; 1.1326x over previous
//
#include <hip/hip_runtime.h>
#include <hip/hip_bf16.h>

#define N_NODES 100000
#define N_EDGES 1600000
#define D_IN    256
#define D_OUT_T 512      // 8 heads * 64, concatenated
#define MPAD    100096   // 782 * 128

#define BM 128
#define BN 128
#define BK 64

#define NB_H2B 25000     // N_NODES*(D_IN/4)/256
#define NB_WCT 512       // 8*256*64/256
#define NB_DEG 6250      // N_EDGES/256

#define NPART 8
#define ROWS_PER_PART (N_NODES / NPART)   // 12500
#define FILL_BLOCKS 2048                  // 256 blocks per partition

typedef __attribute__((ext_vector_type(4))) float f32x4;
typedef __attribute__((ext_vector_type(8))) short bf16x8;
typedef __attribute__((ext_vector_type(4))) unsigned short u16x4;

__device__ __forceinline__ float bf2f(unsigned short u) {
    union { unsigned int i; float f; } x; x.i = ((unsigned int)u) << 16; return x.f;
}
__device__ __forceinline__ unsigned short f2bf(float f) {
    union { float f; unsigned int i; } x; x.f = f;
    unsigned int i = x.i;
    return (unsigned short)((i + 0x7FFFu + ((i >> 16) & 1u)) >> 16);  // RNE
}
__device__ __forceinline__ f32x4 cv4(u16x4 v) {
    f32x4 r; r.x = bf2f(v.x); r.y = bf2f(v.y); r.z = bf2f(v.z); r.w = bf2f(v.w);
    return r;
}

// ---------------- fused preprocessing: h->bf16 | W->WcT bf16 | degree count ----
// WcT[h*64+j][d] = W[h][d][j];  deg via atomics (deg aliased onto rowptr[0..N))
__global__ void k_pre(const float* __restrict__ h, unsigned short* __restrict__ hb,
                      const float* __restrict__ W, unsigned short* __restrict__ WcT,
                      const int* __restrict__ erow, int* __restrict__ deg,
                      int do_hb) {
    int b = blockIdx.x;
    if (b < NB_H2B) {
        if (!do_hb) return;
        int i = b * 256 + threadIdx.x;                 // 6.4M float4 groups
        f32x4 v = ((const f32x4*)h)[i];
        u16x4 o; o.x = f2bf(v.x); o.y = f2bf(v.y); o.z = f2bf(v.z); o.w = f2bf(v.w);
        ((u16x4*)hb)[i] = o;
    } else if (b < NB_H2B + NB_WCT) {
        int t = (b - NB_H2B) * 256 + threadIdx.x;      // 131072
        int hh = t >> 14;
        int rem = t & 16383;
        int d = rem >> 6;
        int j = rem & 63;
        WcT[(size_t)(hh * 64 + j) * 256 + d] = f2bf(W[t]);
    } else {
        int i = (b - NB_H2B - NB_WCT) * 256 + threadIdx.x;
        if (i < N_EDGES) atomicAdd(&deg[erow[i]], 1);
    }
}

// ---------------- 3-kernel exclusive scan over deg -> rowptr ----------------
__global__ void k_scan1(int* __restrict__ deg, int* __restrict__ bsum) {
    __shared__ int sm[256];
    int t = threadIdx.x, i = blockIdx.x * 256 + t;
    int v = (i < N_NODES) ? deg[i] : 0;
    sm[t] = v; __syncthreads();
    #pragma unroll
    for (int o = 1; o < 256; o <<= 1) {
        int x = (t >= o) ? sm[t - o] : 0;
        __syncthreads();
        sm[t] += x;
        __syncthreads();
    }
    if (i < N_NODES) deg[i] = sm[t] - v;      // exclusive within block
    if (t == 255) bsum[blockIdx.x] = sm[255]; // block total
}
__global__ void k_scan2(int* __restrict__ bsum, int nb) {
    __shared__ int sm[512];
    int t = threadIdx.x;
    int v = (t < nb) ? bsum[t] : 0;
    sm[t] = v; __syncthreads();
    #pragma unroll
    for (int o = 1; o < 512; o <<= 1) {
        int x = (t >= o) ? sm[t - o] : 0;
        __syncthreads();
        sm[t] += x;
        __syncthreads();
    }
    if (t < nb) bsum[t] = sm[t] - v;          // exclusive block offsets
}
__global__ void k_scan3(int* __restrict__ rowptr, const int* __restrict__ bsum,
                        int* __restrict__ cursor) {
    int i = blockIdx.x * 256 + threadIdx.x;
    if (i < N_NODES) {
        int v = rowptr[i] + bsum[blockIdx.x];
        rowptr[i] = v;
        cursor[i] = v;
    }
    if (i == 0) rowptr[N_NODES] = N_EDGES;
}

// ---------------- CSR fill, row-range partitioned with XCD affinity ----------
// Partition p = blockIdx&7 (consecutive blockIdx round-robin across the 8 XCDs,
// so all of partition p's blocks share one XCD). Partition p handles only rows
// [p*12500,(p+1)*12500): its colidx positions form ONE contiguous ~800KB region
// written exclusively from that XCD's L2 -> full-line writebacks, no cross-XCD
// partial-line thrash (round-2 counter: WRITE_SIZE 105MB for 6.4MB payload).
__global__ __launch_bounds__(256) void k_fill(const int* __restrict__ erow,
                                              const int* __restrict__ ecol,
                                              int* __restrict__ cursor,
                                              int* __restrict__ colidx) {
    const int part = blockIdx.x & (NPART - 1);
    const int bi   = blockIdx.x >> 3;
    const int lo = part * ROWS_PER_PART;
    const int hi = lo + ROWS_PER_PART;
    const int stride = (FILL_BLOCKS / NPART) * 256;
    for (int i = bi * 256 + threadIdx.x; i < N_EDGES; i += stride) {
        int r = erow[i];
        if (r >= lo && r < hi) {
            int p = atomicAdd(&cursor[r], 1);
            colidx[p] = ecol[i];
        }
    }
}

// ---------------- aggregation: one wave per node, 8-deep MLP ----------------
// hagg[n] = (1/deg) * sum_{e in row n} src[col[e]]   (bf16 out, fp32 accum)
template <bool BF16SRC>
__global__ __launch_bounds__(256) void k_agg(const void* __restrict__ src,
                                             const int* __restrict__ rowptr,
                                             const int* __restrict__ colidx,
                                             unsigned short* __restrict__ hagg) {
    int wid = blockIdx.x * 4 + (threadIdx.x >> 6);
    int lane = threadIdx.x & 63;
    if (wid >= N_NODES) return;
    int s = rowptr[wid], e = rowptr[wid + 1];
    f32x4 acc[8] = {};
    const unsigned short* hb = (const unsigned short*)src;
    const float* hf = (const float*)src;
    int p = s;
    for (; p + 8 <= e; p += 8) {
        int c[8];
        #pragma unroll
        for (int j = 0; j < 8; ++j) c[j] = colidx[p + j];
        if constexpr (BF16SRC) {
            u16x4 v[8];
            #pragma unroll
            for (int j = 0; j < 8; ++j)
                v[j] = *((const u16x4*)(hb + ((size_t)c[j] << 8)) + lane);
            #pragma unroll
            for (int j = 0; j < 8; ++j) acc[j] += cv4(v[j]);
        } else {
            f32x4 v[8];
            #pragma unroll
            for (int j = 0; j < 8; ++j)
                v[j] = *((const f32x4*)(hf + ((size_t)c[j] << 8)) + lane);
            #pragma unroll
            for (int j = 0; j < 8; ++j) acc[j] += v[j];
        }
    }
    if (p + 4 <= e) {
        int c[4];
        #pragma unroll
        for (int j = 0; j < 4; ++j) c[j] = colidx[p + j];
        if constexpr (BF16SRC) {
            u16x4 v[4];
            #pragma unroll
            for (int j = 0; j < 4; ++j)
                v[j] = *((const u16x4*)(hb + ((size_t)c[j] << 8)) + lane);
            #pragma unroll
            for (int j = 0; j < 4; ++j) acc[j] += cv4(v[j]);
        } else {
            f32x4 v[4];
            #pragma unroll
            for (int j = 0; j < 4; ++j)
                v[j] = *((const f32x4*)(hf + ((size_t)c[j] << 8)) + lane);
            #pragma unroll
            for (int j = 0; j < 4; ++j) acc[j] += v[j];
        }
        p += 4;
    }
    for (; p < e; ++p) {
        int c = colidx[p];
        if constexpr (BF16SRC) {
            acc[0] += cv4(*((const u16x4*)(hb + ((size_t)c << 8)) + lane));
        } else {
            acc[0] += *((const f32x4*)(hf + ((size_t)c << 8)) + lane);
        }
    }
    #pragma unroll
    for (int j = 4; j < 8; ++j) acc[j - 4] += acc[j];
    acc[0] += acc[2]; acc[1] += acc[3]; acc[0] += acc[1];
    float inv = (e > s) ? 1.0f / (float)(e - s) : 0.0f;
    u16x4 o;
    o.x = f2bf(acc[0].x * inv); o.y = f2bf(acc[0].y * inv);
    o.z = f2bf(acc[0].z * inv); o.w = f2bf(acc[0].w * inv);
    *((u16x4*)(hagg + ((size_t)wid << 8)) + lane) = o;
}

// ---------------- GEMM: C[M x 512] = hagg[M x 256] * Wc[256 x 512] ----------------
// A = hagg row-major [MPAD][256] bf16; B = WcT row-major [512][256] bf16 (i.e. Wc^T)
// 128x128 block tile, 4 waves (2x2), each wave 64x64, BK=64, 16x16x32 bf16 MFMA.
// LDS tiles stored as [rows][64] with 16B-chunk XOR swizzle (chunk ^= row&7):
// linear global_load_lds dest + inverse-swizzled global src + swizzled ds_read.
// 1D grid with XCD-chunk swizzle: the 4 N-blocks sharing an A panel are
// consecutive on the same XCD -> A fetched ~once from HBM.
__global__ __launch_bounds__(256, 2) void k_gemm(const unsigned short* __restrict__ A,
                                                 const unsigned short* __restrict__ B,
                                                 float* __restrict__ C, int M) {
    __shared__ __align__(16) unsigned short As[BM * BK];
    __shared__ __align__(16) unsigned short Bs[BN * BK];
    const int orig = blockIdx.x;                   // 3128 = 782*4, 3128%8==0
    const int wgid = (orig & 7) * (3128 / 8) + (orig >> 3);
    const int M0 = (wgid >> 2) * BM;
    const int N0 = (wgid & 3) * BN;
    const int tid  = threadIdx.x;
    const int wave = tid >> 6;
    const int lane = tid & 63;
    const int wm = (wave >> 1) * 64;
    const int wn = (wave & 1) * 64;

    f32x4 acc[4][4] = {};

    for (int kk = 0; kk < D_IN; kk += BK) {
        __syncthreads();  // previous-iteration LDS reads done before overwrite
        #pragma unroll
        for (int i = 0; i < 4; ++i) {  // stage A tile: 128 rows x 64 k
            int rbase = i * 32 + wave * 8;
            int r = rbase + (lane >> 3);
            int gc = (lane & 7) ^ (r & 7);  // inverse-swizzled source chunk
            const unsigned short* g = A + (size_t)(M0 + r) * D_IN + kk + gc * 8;
            __builtin_amdgcn_global_load_lds(
                (const __attribute__((address_space(1))) void*)g,
                (__attribute__((address_space(3))) void*)(As + rbase * 64), 16, 0, 0);
        }
        #pragma unroll
        for (int i = 0; i < 4; ++i) {  // stage B tile: 128 cols x 64 k
            int rbase = i * 32 + wave * 8;
            int r = rbase + (lane >> 3);
            int gc = (lane & 7) ^ (r & 7);
            const unsigned short* g = B + (size_t)(N0 + r) * D_IN + kk + gc * 8;
            __builtin_amdgcn_global_load_lds(
                (const __attribute__((address_space(1))) void*)g,
                (__attribute__((address_space(3))) void*)(Bs + rbase * 64), 16, 0, 0);
        }
        __syncthreads();

        #pragma unroll
        for (int ks = 0; ks < 2; ++ks) {
            bf16x8 a[4], b[4];
            #pragma unroll
            for (int m = 0; m < 4; ++m) {
                int r = wm + m * 16 + (lane & 15);
                int lc = (ks * 4 + (lane >> 4)) ^ (r & 7);  // swizzled read chunk
                a[m] = *(const bf16x8*)(As + r * 64 + lc * 8);
            }
            #pragma unroll
            for (int n = 0; n < 4; ++n) {
                int c = wn + n * 16 + (lane & 15);
                int lc = (ks * 4 + (lane >> 4)) ^ (c & 7);
                b[n] = *(const bf16x8*)(Bs + c * 64 + lc * 8);
            }
            #pragma unroll
            for (int m = 0; m < 4; ++m)
                #pragma unroll
                for (int n = 0; n < 4; ++n)
                    acc[m][n] = __builtin_amdgcn_mfma_f32_16x16x32_bf16(
                        a[m], b[n], acc[m][n], 0, 0, 0);
        }
    }

    // C/D layout: col = lane&15, row = (lane>>4)*4 + reg
    #pragma unroll
    for (int m = 0; m < 4; ++m) {
        #pragma unroll
        for (int i = 0; i < 4; ++i) {
            int row = M0 + wm + m * 16 + (lane >> 4) * 4 + i;
            if (row < M) {
                #pragma unroll
                for (int n = 0; n < 4; ++n) {
                    int col = N0 + wn + n * 16 + (lane & 15);
                    C[(size_t)row * D_OUT_T + col] = acc[m][n][i];
                }
            }
        }
    }
}

extern "C" void kernel_launch(void* const* d_in, const int* in_sizes, int n_in,
                              void* d_out, int out_size, void* d_ws, size_t ws_size,
                              hipStream_t stream) {
    const float* h  = (const float*)d_in[0];
    const float* W  = (const float*)d_in[1];
    const int* erow = (const int*)d_in[2];
    const int* ecol = erow + N_EDGES;
    float* out = (float*)d_out;

    char* base = (char*)d_ws;
    size_t off = 0;
    auto alloc = [&](size_t b) {
        char* p = base + off;
        off += (b + 255) & ~(size_t)255;
        return p;
    };
    int* rowptr = (int*)alloc((N_NODES + 1) * sizeof(int));  // doubles as deg
    int* cursor = (int*)alloc(N_NODES * sizeof(int));
    int* bsum   = (int*)alloc(512 * sizeof(int));
    int* colidx = (int*)alloc((size_t)N_EDGES * sizeof(int));
    unsigned short* WcT  = (unsigned short*)alloc((size_t)D_OUT_T * D_IN * 2);
    unsigned short* hagg = (unsigned short*)alloc((size_t)MPAD * D_IN * 2);
    unsigned short* hb   = (unsigned short*)alloc((size_t)N_NODES * D_IN * 2);
    bool use_hb = (off <= ws_size);  // fall back to fp32 gather if ws too small

    hipMemsetAsync(rowptr, 0, (N_NODES + 1) * sizeof(int), stream);

    k_pre<<<NB_H2B + NB_WCT + NB_DEG, 256, 0, stream>>>(
        h, hb, W, WcT, erow, rowptr, use_hb ? 1 : 0);

    const int NB = (N_NODES + 255) / 256;  // 391
    k_scan1<<<NB, 256, 0, stream>>>(rowptr, bsum);
    k_scan2<<<1, 512, 0, stream>>>(bsum, NB);
    k_scan3<<<NB, 256, 0, stream>>>(rowptr, bsum, cursor);
    k_fill<<<FILL_BLOCKS, 256, 0, stream>>>(erow, ecol, cursor, colidx);

    if (use_hb)
        k_agg<true><<<(N_NODES + 3) / 4, 256, 0, stream>>>(hb, rowptr, colidx, hagg);
    else
        k_agg<false><<<(N_NODES + 3) / 4, 256, 0, stream>>>(h, rowptr, colidx, hagg);

    k_gemm<<<MPAD / BM * 4, 256, 0, stream>>>(hagg, WcT, out, N_NODES);
}